// Round 1
// baseline (1561.235 us; speedup 1.0000x reference)
//
#include <hip/hip_runtime.h>
#include <math.h>

// TVKoopmanMoE: B=4096, C=128, D=32, K=8, R=8, NSEG=3, STEPS=8 each, DT=0.1
// Strategy:
//  - w, diag^2 via tiny per-b kernel (kA)
//  - weighted skew sum folded into ONE GEMM: Shat = LHS @ V2,
//    LHS[b,(k,c)] = w[b,k]*ctx[b,c], V2[(k,c),n] = S_W[c,k,n] - S_W[c,k,nT]  (kB0,kB2)
//  - sum_k w_k L_k L_k^T = Ltil Ltil^T with Ltil = sqrt(w_k)*rawL_k   (kL, kLLT)
//  - per-b expm via block-triangular Taylor (ORDER=8) + 2 squarings + propagation (kC)

#define NSEGC 3
#define BSZ   4096
#define MUC   0.14861455999447191f   /* -ln(0.7)/(0.1*24) */
#define XSC   0.025f                 /* DT / 2^SQ = 0.1/4 */

__device__ __forceinline__ void ld4(float d[4], const float* p) {
  const float4 v = *(const float4*)p; d[0]=v.x; d[1]=v.y; d[2]=v.z; d[3]=v.w;
}
__device__ __forceinline__ void ld2(float d[2], const float* p) {
  const float2 v = *(const float2*)p; d[0]=v.x; d[1]=v.y;
}
__device__ __forceinline__ void st4(float* p, const float d[4]) {
  *(float4*)p = make_float4(d[0], d[1], d[2], d[3]);
}

// ---------------- kA: gates (softmax(logits/2)) and diag^2 ----------------
__global__ __launch_bounds__(64) void kA(const float* __restrict__ ctx,
    const float* __restrict__ GW, const float* __restrict__ Gb,
    const float* __restrict__ SgW, const float* __restrict__ Sgb,
    float* __restrict__ Wsm, float* __restrict__ Q2) {
  const int b = blockIdx.x, s = blockIdx.y, l = threadIdx.x;
  __shared__ float c[128];
  c[l]      = ctx[(size_t)b*128 + l];
  c[l + 64] = ctx[(size_t)b*128 + 64 + l];
  __syncthreads();
  if (l < 8) {
    float acc = Gb[s*8 + l];
    #pragma unroll 4
    for (int q = 0; q < 128; ++q) acc += c[q] * GW[(size_t)(s*128 + q)*8 + l];
    float li = acc * 0.5f;            // / TEMP (=2)
    float m = li;
    m = fmaxf(m, __shfl_xor(m, 1));
    m = fmaxf(m, __shfl_xor(m, 2));
    m = fmaxf(m, __shfl_xor(m, 4));
    float e = expf(li - m);
    float sum = e;
    sum += __shfl_xor(sum, 1);
    sum += __shfl_xor(sum, 2);
    sum += __shfl_xor(sum, 4);
    Wsm[((size_t)s*BSZ + b)*8 + l] = e / sum;
  } else if (l < 40) {
    const int d = l - 8;
    float acc = Sgb[s*32 + d];
    #pragma unroll 4
    for (int q = 0; q < 128; ++q) acc += c[q] * SgW[(size_t)(s*128 + q)*32 + d];
    float sp = fmaxf(acc, 0.f) + log1pf(expf(-fabsf(acc)));  // stable softplus
    float dg = fminf(sp, 1.0f);
    Q2[((size_t)s*BSZ + b)*32 + d] = dg * dg;
  }
}

// ---------------- kA2: ctxT[c][b] = ctx[b][c] ----------------
__global__ __launch_bounds__(256) void kA2(const float* __restrict__ ctx,
                                           float* __restrict__ ctxT) {
  __shared__ float tile[32][33];
  const int bb = blockIdx.x * 32, cc = blockIdx.y * 32;
  const int tx = threadIdx.x & 31, ty = threadIdx.x >> 5;
  for (int r = ty; r < 32; r += 8) tile[r][tx] = ctx[(size_t)(bb + r)*128 + cc + tx];
  __syncthreads();
  for (int r = ty; r < 32; r += 8) ctxT[(size_t)(cc + r)*BSZ + bb + tx] = tile[tx][r];
}

// ---------------- kB0: V2[s][(k,c)][n] = S_W[c][k,n] - S_W[c][k,nT] ----------------
__global__ __launch_bounds__(256) void kB0(const float* __restrict__ SW,
                                           float* __restrict__ V2) {
  const int kc = blockIdx.x, s = blockIdx.y;
  const int k = kc >> 7, c = kc & 127;
  const float* src = SW + ((size_t)(s*128 + c))*8192 + (size_t)k*1024;
  float* dst = V2 + (size_t)s*1048576 + (size_t)kc*1024;
  for (int n = threadIdx.x; n < 1024; n += 256) {
    const int i = n >> 5, j = n & 31;
    dst[n] = src[n] - src[j*32 + i];
  }
}

// ---------------- kB0b: skewed S_b ----------------
__global__ __launch_bounds__(256) void kB0b(const float* __restrict__ Sb,
                                            float* __restrict__ SBsk) {
  const int k = blockIdx.x, s = blockIdx.y;
  const float* src = Sb + (size_t)s*8192 + (size_t)k*1024;
  for (int n = threadIdx.x; n < 1024; n += 256)
    SBsk[(size_t)(s*8 + k)*1024 + n] = src[n] - src[(n & 31)*32 + (n >> 5)];
}

// ---------------- kB2: AS = (w (x) ctx) @ V2 + bias  (M=4096,K=1024,N=1024) ----------------
__global__ __launch_bounds__(256) void kB2(const float* __restrict__ ctxT,
    const float* __restrict__ Wsm, const float* __restrict__ V2,
    const float* __restrict__ SB, float* __restrict__ AS) {
  __shared__ float At[32][128];
  __shared__ float Bt[32][128];
  __shared__ float wS[8][128];
  __shared__ float sbS[8][128];
  const int t = threadIdx.x;
  const int nb = blockIdx.x * 128, bb = blockIdx.y * 128, s = blockIdx.z;
  for (int i = t; i < 1024; i += 256) {
    const int k = i >> 7, x = i & 127;
    wS[k][x]  = Wsm[((size_t)s*BSZ + bb + x)*8 + k];
    sbS[k][x] = SB[(size_t)(s*8 + k)*1024 + nb + x];
  }
  float acc[8][8] = {};
  const int b0 = (t >> 4) * 8, n0 = (t & 15) * 8;
  const int qrow = t >> 3, x0 = (t & 7) * 16;
  for (int kc0 = 0; kc0 < 1024; kc0 += 32) {
    const int kseg = kc0 >> 7, cbase = kc0 & 127;
    __syncthreads();
    #pragma unroll
    for (int rep = 0; rep < 4; ++rep) {
      const int x = x0 + rep*4;
      const float4 cv = *(const float4*)&ctxT[(size_t)(cbase + qrow)*BSZ + bb + x];
      const float4 wv = *(const float4*)&wS[kseg][x];
      *(float4*)&At[qrow][x] = make_float4(cv.x*wv.x, cv.y*wv.y, cv.z*wv.z, cv.w*wv.w);
      *(float4*)&Bt[qrow][x] =
        *(const float4*)&V2[(size_t)s*1048576 + (size_t)(kc0 + qrow)*1024 + nb + x];
    }
    __syncthreads();
    #pragma unroll 8
    for (int q = 0; q < 32; ++q) {
      float av[8], bv[8];
      ld4(av, &At[q][b0]); ld4(av + 4, &At[q][b0 + 4]);
      ld4(bv, &Bt[q][n0]); ld4(bv + 4, &Bt[q][n0 + 4]);
      #pragma unroll
      for (int i = 0; i < 8; ++i)
        #pragma unroll
        for (int j = 0; j < 8; ++j) acc[i][j] += av[i] * bv[j];
    }
  }
  // bias: + sum_k w[b,k]*SBsk[k,n]
  #pragma unroll
  for (int k = 0; k < 8; ++k) {
    float wv[8], sv[8];
    ld4(wv, &wS[k][b0]); ld4(wv + 4, &wS[k][b0 + 4]);
    ld4(sv, &sbS[k][n0]); ld4(sv + 4, &sbS[k][n0 + 4]);
    #pragma unroll
    for (int i = 0; i < 8; ++i)
      #pragma unroll
      for (int j = 0; j < 8; ++j) acc[i][j] += wv[i] * sv[j];
  }
  for (int i = 0; i < 8; ++i) {
    float* dst = AS + ((size_t)s*BSZ + bb + b0 + i)*1024 + nb + n0;
    st4(dst, acc[i]); st4(dst + 4, &acc[i][4]);
  }
}

// ---------------- kL: Ltil = (ctx@L_W + L_b)*sqrt(w)  -> LT[b][(k*8+r)*32+d] ----------------
__global__ __launch_bounds__(256) void kL(const float* __restrict__ ctxT,
    const float* __restrict__ LW, const float* __restrict__ Lb,
    const float* __restrict__ Wsm, float* __restrict__ LT, int s) {
  __shared__ float At[32][128];
  __shared__ float Bt[32][128];
  __shared__ float wsq[8][128];
  const int t = threadIdx.x;
  const int nb = blockIdx.x * 128, bb = blockIdx.y * 128;
  for (int i = t; i < 1024; i += 256) {
    const int k = i >> 7, x = i & 127;
    wsq[k][x] = sqrtf(Wsm[((size_t)s*BSZ + bb + x)*8 + k]);
  }
  float acc[8][8] = {};
  const int b0 = (t >> 4) * 8, n0 = (t & 15) * 8;
  const int qrow = t >> 3, x0 = (t & 7) * 16;
  for (int c0 = 0; c0 < 128; c0 += 32) {
    __syncthreads();
    #pragma unroll
    for (int rep = 0; rep < 4; ++rep) {
      const int x = x0 + rep*4;
      *(float4*)&At[qrow][x] = *(const float4*)&ctxT[(size_t)(c0 + qrow)*BSZ + bb + x];
      *(float4*)&Bt[qrow][x] =
        *(const float4*)&LW[((size_t)(s*128 + c0 + qrow))*2048 + nb + x];
    }
    __syncthreads();
    #pragma unroll 8
    for (int q = 0; q < 32; ++q) {
      float av[8], bv[8];
      ld4(av, &At[q][b0]); ld4(av + 4, &At[q][b0 + 4]);
      ld4(bv, &Bt[q][n0]); ld4(bv + 4, &Bt[q][n0 + 4]);
      #pragma unroll
      for (int i = 0; i < 8; ++i)
        #pragma unroll
        for (int j = 0; j < 8; ++j) acc[i][j] += av[i] * bv[j];
    }
  }
  const int kidx = (nb + n0) >> 8;
  const int dcol = ((nb + n0) >> 3) & 31;
  float lbv[8];
  #pragma unroll
  for (int j = 0; j < 8; ++j) lbv[j] = Lb[(size_t)s*2048 + nb + n0 + j];
  for (int i = 0; i < 8; ++i) {
    const float wv = wsq[kidx][b0 + i];
    float* dst = LT + (size_t)(bb + b0 + i)*2048 + kidx*256 + dcol;
    #pragma unroll
    for (int j = 0; j < 8; ++j) dst[j*32] = (acc[i][j] + lbv[j]) * wv;  // r=j stride 32
  }
}

// ---------------- kLLT: AS -= Ltil Ltil^T  (4 b per block) ----------------
__global__ __launch_bounds__(128) void kLLT(const float* __restrict__ LT,
                                            float* __restrict__ AS, int s) {
  __shared__ float L4[4][64][32];
  const int t = threadIdx.x;
  const int bbase = blockIdx.x * 4;
  {
    float* l4f = &L4[0][0][0];
    const float* src = LT + (size_t)bbase * 2048;
    for (int i = t*4; i < 8192; i += 512)
      *(float4*)&l4f[i] = *(const float4*)&src[i];
  }
  __syncthreads();
  const int b = t >> 5, u = t & 31;
  const int i0 = (u >> 2) * 4, j0 = (u & 3) * 8;
  float acc[4][8] = {};
  #pragma unroll 8
  for (int kr = 0; kr < 64; ++kr) {
    float pa[4], pb[8];
    ld4(pa, &L4[b][kr][i0]);
    ld4(pb, &L4[b][kr][j0]); ld4(pb + 4, &L4[b][kr][j0 + 4]);
    #pragma unroll
    for (int ii = 0; ii < 4; ++ii)
      #pragma unroll
      for (int jj = 0; jj < 8; ++jj) acc[ii][jj] += pa[ii] * pb[jj];
  }
  float* dst = AS + ((size_t)s*BSZ + bbase + b)*1024;
  for (int ii = 0; ii < 4; ++ii) {
    float x[8];
    ld4(x, &dst[(i0+ii)*32 + j0]); ld4(x + 4, &dst[(i0+ii)*32 + j0 + 4]);
    #pragma unroll
    for (int jj = 0; jj < 8; ++jj) x[jj] -= acc[ii][jj];
    st4(&dst[(i0+ii)*32 + j0], x); st4(&dst[(i0+ii)*32 + j0 + 4], &x[4]);
  }
}

// ---------------- kC: per-b expm (block triangular) + propagation ----------------
// 128 threads per block, one b per block. Thread tile: rows {r0,r0+1} x cols {c0..c0+3}.
// All matmul A-operands read via explicitly maintained transposed copies (row reads only).
__global__ __launch_bounds__(128, 2) void kC(const float* __restrict__ AS,
    const float* __restrict__ Q2, const float* __restrict__ z0,
    float* __restrict__ out) {
  __shared__ float a[32][32], aT[32][32];
  __shared__ float R11[32][32], R11T[32][32];
  __shared__ float R12[32][32], R12T[32][32];
  __shared__ float R22[32][32], R22T[32][32];
  __shared__ float cov[32][32];
  __shared__ float zv[32], qd[32], red[2];
  const int b = blockIdx.x, t = threadIdx.x;
  const int r0 = (t >> 3) * 2, c0 = (t & 7) * 4;
  if (t < 32) zv[t] = z0[(size_t)b*32 + t];
  {
    const float4 zz = make_float4(0.f, 0.f, 0.f, 0.f);
    *(float4*)&cov[r0][c0] = zz; *(float4*)&cov[r0+1][c0] = zz;
  }
  __syncthreads();
  float* covout = out + 3145728 + (size_t)b*24576;
  float* stout  = out + (size_t)b*768;

  for (int s = 0; s < NSEGC; ++s) {
    // ---- load A tile, frob clamp, build a (=A*DT/4), aT, qd, init R ----
    const float* asb = AS + ((size_t)s*BSZ + b)*1024;
    float At0[4], At1[4];
    ld4(At0, &asb[r0*32 + c0]); ld4(At1, &asb[(r0+1)*32 + c0]);
    #pragma unroll
    for (int j = 0; j < 4; ++j) {
      if (r0     == c0 + j) At0[j] -= MUC;
      if (r0 + 1 == c0 + j) At1[j] -= MUC;
    }
    float ssq = 0.f;
    #pragma unroll
    for (int j = 0; j < 4; ++j) ssq += At0[j]*At0[j] + At1[j]*At1[j];
    #pragma unroll
    for (int off = 1; off < 64; off <<= 1) ssq += __shfl_xor(ssq, off);
    if ((t & 63) == 0) red[t >> 6] = ssq;
    __syncthreads();
    const float frob = sqrtf(red[0] + red[1]);
    const float sc = (frob > 3.0f ? 3.0f / (frob + 1e-6f) : 1.0f) * XSC;
    if (t < 32) qd[t] = Q2[((size_t)s*BSZ + b)*32 + t] * XSC;
    #pragma unroll
    for (int j = 0; j < 4; ++j) {
      const float v0 = At0[j]*sc, v1 = At1[j]*sc;
      a[r0][c0+j] = v0;  a[r0+1][c0+j] = v1;
      aT[c0+j][r0] = v0; aT[c0+j][r0+1] = v1;
      const float e0 = (r0     == c0+j) ? 1.f : 0.f;
      const float e1 = (r0 + 1 == c0+j) ? 1.f : 0.f;
      R11[r0][c0+j] = e0;  R11[r0+1][c0+j] = e1;
      R11T[c0+j][r0] = e0; R11T[c0+j][r0+1] = e1;
      R22[r0][c0+j] = e0;  R22[r0+1][c0+j] = e1;
      R22T[c0+j][r0] = e0; R22T[c0+j][r0+1] = e1;
      R12[r0][c0+j] = 0.f; R12[r0+1][c0+j] = 0.f;
      R12T[c0+j][r0] = 0.f; R12T[c0+j][r0+1] = 0.f;
    }
    __syncthreads();

    // ---- Taylor (Horner), ORDER=8:  R = I + X @ R / k, X = [[a,q],[0,-a^T]] ----
    for (int k = 8; k >= 1; --k) {
      float A11[2][4] = {}, A12[2][4] = {}, A22[2][4] = {};
      #pragma unroll 8
      for (int kk = 0; kk < 32; ++kk) {
        float pa[2], pn[2], q11[4], q12[4], q22[4];
        ld2(pa, &aT[kk][r0]); ld2(pn, &a[kk][r0]);
        ld4(q11, &R11[kk][c0]); ld4(q12, &R12[kk][c0]); ld4(q22, &R22[kk][c0]);
        #pragma unroll
        for (int ii = 0; ii < 2; ++ii)
          #pragma unroll
          for (int j = 0; j < 4; ++j) {
            A11[ii][j] += pa[ii] * q11[j];
            A12[ii][j] += pa[ii] * q12[j];
            A22[ii][j] -= pn[ii] * q22[j];   // (-a^T) @ R22
          }
      }
      float rq0[4], rq1[4];
      ld4(rq0, &R22[r0][c0]); ld4(rq1, &R22[r0+1][c0]);
      const float rk = 1.0f / (float)k;
      const float qd0 = qd[r0], qd1 = qd[r0+1];
      float n11_0[4], n11_1[4], n12_0[4], n12_1[4], n22_0[4], n22_1[4];
      #pragma unroll
      for (int j = 0; j < 4; ++j) {
        const float e0 = (r0     == c0+j) ? 1.f : 0.f;
        const float e1 = (r0 + 1 == c0+j) ? 1.f : 0.f;
        n11_0[j] = A11[0][j]*rk + e0;
        n11_1[j] = A11[1][j]*rk + e1;
        n12_0[j] = (A12[0][j] + qd0*rq0[j]) * rk;
        n12_1[j] = (A12[1][j] + qd1*rq1[j]) * rk;
        n22_0[j] = A22[0][j]*rk + e0;
        n22_1[j] = A22[1][j]*rk + e1;
      }
      __syncthreads();
      st4(&R11[r0][c0], n11_0); st4(&R11[r0+1][c0], n11_1);
      st4(&R12[r0][c0], n12_0); st4(&R12[r0+1][c0], n12_1);
      st4(&R22[r0][c0], n22_0); st4(&R22[r0+1][c0], n22_1);
      #pragma unroll
      for (int j = 0; j < 4; ++j) {
        *(float2*)&R11T[c0+j][r0] = make_float2(n11_0[j], n11_1[j]);
        *(float2*)&R12T[c0+j][r0] = make_float2(n12_0[j], n12_1[j]);
        *(float2*)&R22T[c0+j][r0] = make_float2(n22_0[j], n22_1[j]);
      }
      __syncthreads();
    }

    // ---- 2 squarings of block-triangular E ----
    for (int sq = 0; sq < 2; ++sq) {
      float A11[2][4] = {}, A12[2][4] = {}, A22[2][4] = {};
      #pragma unroll 8
      for (int kk = 0; kk < 32; ++kk) {
        float p11[2], p12[2], p22[2], q11[4], q12[4], q22[4];
        ld2(p11, &R11T[kk][r0]); ld2(p12, &R12T[kk][r0]); ld2(p22, &R22T[kk][r0]);
        ld4(q11, &R11[kk][c0]); ld4(q12, &R12[kk][c0]); ld4(q22, &R22[kk][c0]);
        #pragma unroll
        for (int ii = 0; ii < 2; ++ii)
          #pragma unroll
          for (int j = 0; j < 4; ++j) {
            A11[ii][j] += p11[ii] * q11[j];
            A12[ii][j] += p11[ii] * q12[j] + p12[ii] * q22[j];
            A22[ii][j] += p22[ii] * q22[j];
          }
      }
      __syncthreads();
      st4(&R11[r0][c0], A11[0]); st4(&R11[r0+1][c0], A11[1]);
      st4(&R12[r0][c0], A12[0]); st4(&R12[r0+1][c0], A12[1]);
      st4(&R22[r0][c0], A22[0]); st4(&R22[r0+1][c0], A22[1]);
      #pragma unroll
      for (int j = 0; j < 4; ++j) {
        *(float2*)&R11T[c0+j][r0] = make_float2(A11[0][j], A11[1][j]);
        *(float2*)&R12T[c0+j][r0] = make_float2(A12[0][j], A12[1][j]);
        *(float2*)&R22T[c0+j][r0] = make_float2(A22[0][j], A22[1][j]);
      }
      __syncthreads();
    }

    // ---- Qd = 0.5*(Phi@E12 + (Phi@E12)^T)  -> store into R22 buffer ----
    {
      float AA[2][4] = {}, BB[2][4] = {};
      #pragma unroll 8
      for (int kk = 0; kk < 32; ++kk) {
        float p1[2], p2[2], q12[4], q11t[4];
        ld2(p1, &R11T[kk][r0]);  // Phi[i][kk]
        ld2(p2, &R12[kk][r0]);   // E12[kk][i]
        ld4(q12, &R12[kk][c0]);  // E12[kk][j]
        ld4(q11t, &R11T[kk][c0]);// Phi[j][kk]
        #pragma unroll
        for (int ii = 0; ii < 2; ++ii)
          #pragma unroll
          for (int j = 0; j < 4; ++j) {
            AA[ii][j] += p1[ii] * q12[j];
            BB[ii][j] += p2[ii] * q11t[j];
          }
      }
      float q0[4], q1[4];
      #pragma unroll
      for (int j = 0; j < 4; ++j) {
        q0[j] = 0.5f * (AA[0][j] + BB[0][j]);
        q1[j] = 0.5f * (AA[1][j] + BB[1][j]);
      }
      __syncthreads();
      st4(&R22[r0][c0], q0); st4(&R22[r0+1][c0], q1);
      __syncthreads();
    }

    // ---- 8 propagation steps ----
    for (int tt = 0; tt < 8; ++tt) {
      // P1: T1 = Phi @ cov (into R12/R12T), z' = Phi @ z
      float T1[2][4] = {};
      #pragma unroll 8
      for (int kk = 0; kk < 32; ++kk) {
        float p[2], cvv[4];
        ld2(p, &R11T[kk][r0]);
        ld4(cvv, &cov[kk][c0]);
        #pragma unroll
        for (int ii = 0; ii < 2; ++ii)
          #pragma unroll
          for (int j = 0; j < 4; ++j) T1[ii][j] += p[ii] * cvv[j];
      }
      float zn = 0.f;
      if (t < 32) {
        #pragma unroll 8
        for (int kk = 0; kk < 32; ++kk) zn += R11T[kk][t] * zv[kk];
      }
      __syncthreads();
      st4(&R12[r0][c0], T1[0]); st4(&R12[r0+1][c0], T1[1]);
      #pragma unroll
      for (int j = 0; j < 4; ++j)
        *(float2*)&R12T[c0+j][r0] = make_float2(T1[0][j], T1[1][j]);
      if (t < 32) zv[t] = zn;
      __syncthreads();
      // P2: cov' = 0.5*(T1@Phi^T + Phi@T1^T) + Qd
      float C1[2][4] = {}, C2[2][4] = {};
      #pragma unroll 8
      for (int kk = 0; kk < 32; ++kk) {
        float pA[2], pB[2], bA[4], bB[4];
        ld2(pA, &R12T[kk][r0]);  // T1[i][kk]
        ld2(pB, &R11T[kk][r0]);  // Phi[i][kk]
        ld4(bA, &R11T[kk][c0]);  // Phi[j][kk]
        ld4(bB, &R12T[kk][c0]);  // T1[j][kk]
        #pragma unroll
        for (int ii = 0; ii < 2; ++ii)
          #pragma unroll
          for (int j = 0; j < 4; ++j) {
            C1[ii][j] += pA[ii] * bA[j];
            C2[ii][j] += pB[ii] * bB[j];
          }
      }
      float qdt0[4], qdt1[4];
      ld4(qdt0, &R22[r0][c0]); ld4(qdt1, &R22[r0+1][c0]);
      float cv0[4], cv1[4];
      #pragma unroll
      for (int j = 0; j < 4; ++j) {
        cv0[j] = 0.5f * (C1[0][j] + C2[0][j]) + qdt0[j];
        cv1[j] = 0.5f * (C1[1][j] + C2[1][j]) + qdt1[j];
      }
      __syncthreads();
      st4(&cov[r0][c0], cv0); st4(&cov[r0+1][c0], cv1);
      float* cb = covout + (size_t)(s*8 + tt)*1024;
      st4(&cb[r0*32 + c0], cv0); st4(&cb[(r0+1)*32 + c0], cv1);
      if (t < 32) stout[(s*8 + tt)*32 + t] = zv[t];
      __syncthreads();
    }
  }
}

// ---------------- launch ----------------
extern "C" void kernel_launch(void* const* d_in, const int* in_sizes, int n_in,
                              void* d_out, int out_size, void* d_ws, size_t ws_size,
                              hipStream_t stream) {
  const float* ctx  = (const float*)d_in[0];
  const float* z0   = (const float*)d_in[1];
  const float* S_W  = (const float*)d_in[2];
  const float* S_b  = (const float*)d_in[3];
  const float* L_W  = (const float*)d_in[4];
  const float* L_b  = (const float*)d_in[5];
  const float* G_W  = (const float*)d_in[6];
  const float* G_b  = (const float*)d_in[7];
  const float* Sg_W = (const float*)d_in[8];
  const float* Sg_b = (const float*)d_in[9];
  float* out = (float*)d_out;
  float* ws  = (float*)d_ws;

  // ws layout (floats); total 25,157,632 floats = 100.6 MB
  float* w_   = ws;                 // [3][4096][8]
  float* q2   = ws + 98304;         // [3][4096][32]
  float* ctxT = ws + 491520;        // [128][4096]
  float* sbsk = ws + 1015808;       // [3][8][1024]
  float* v2   = ws + 1040384;       // [3][1024][1024]
  float* as_  = ws + 4186112;       // [3][4096][1024]
  float* lt   = ws + 16769024;      // [4096][2048] (per-seg reuse)

  kA  <<<dim3(4096, 3), 64,  0, stream>>>(ctx, G_W, G_b, Sg_W, Sg_b, w_, q2);
  kA2 <<<dim3(128, 4),  256, 0, stream>>>(ctx, ctxT);
  kB0 <<<dim3(1024, 3), 256, 0, stream>>>(S_W, v2);
  kB0b<<<dim3(8, 3),    256, 0, stream>>>(S_b, sbsk);
  kB2 <<<dim3(8, 32, 3),256, 0, stream>>>(ctxT, w_, v2, sbsk, as_);
  for (int s = 0; s < 3; ++s) {
    kL  <<<dim3(16, 32), 256, 0, stream>>>(ctxT, L_W, L_b, w_, lt, s);
    kLLT<<<dim3(1024),   128, 0, stream>>>(lt, as_, s);
  }
  kC  <<<dim3(4096),    128, 0, stream>>>(as_, q2, z0, out);
}

// Round 2
// 1296.108 us; speedup vs baseline: 1.2046x; 1.2046x over previous
//
#include <hip/hip_runtime.h>
#include <math.h>

// TVKoopmanMoE: B=4096, C=128, D=32, K=8, R=8, NSEG=3, STEPS=8 each, DT=0.1
//  - w, diag^2 via tiny per-b kernel (kA)
//  - weighted skew sum folded into ONE GEMM: Shat = LHS @ V2 (kB0,kB2)
//  - sum_k w_k L_k L_k^T = Ltil Ltil^T with Ltil = sqrt(w_k)*rawL_k (kL, kLLT)
//  - kC2: ONE WAVE PER b. Block-triangular expm Taylor ORDER=6 + 2 squarings +
//    8-step propagation; 4x4 reg tiles, pad-36 LDS, all b128 row reads,
//    transposed copies written from local register-tile transpose (conflict-free).

#define NSEGC 3
#define BSZ   4096
#define MUC   0.14861455999447191f   /* -ln(0.7)/(0.1*24) */
#define XSC   0.025f                 /* DT / 2^SQ = 0.1/4 */
#define PAD   36

__device__ __forceinline__ void ld4(float d[4], const float* p) {
  const float4 v = *(const float4*)p; d[0]=v.x; d[1]=v.y; d[2]=v.z; d[3]=v.w;
}
__device__ __forceinline__ void st4(float* p, const float d[4]) {
  *(float4*)p = make_float4(d[0], d[1], d[2], d[3]);
}

// ---------------- kA: gates (softmax(logits/2)) and diag^2 ----------------
__global__ __launch_bounds__(64) void kA(const float* __restrict__ ctx,
    const float* __restrict__ GW, const float* __restrict__ Gb,
    const float* __restrict__ SgW, const float* __restrict__ Sgb,
    float* __restrict__ Wsm, float* __restrict__ Q2) {
  const int b = blockIdx.x, s = blockIdx.y, l = threadIdx.x;
  __shared__ float c[128];
  c[l]      = ctx[(size_t)b*128 + l];
  c[l + 64] = ctx[(size_t)b*128 + 64 + l];
  __syncthreads();
  if (l < 8) {
    float acc = Gb[s*8 + l];
    #pragma unroll 4
    for (int q = 0; q < 128; ++q) acc += c[q] * GW[(size_t)(s*128 + q)*8 + l];
    float li = acc * 0.5f;            // / TEMP (=2)
    float m = li;
    m = fmaxf(m, __shfl_xor(m, 1));
    m = fmaxf(m, __shfl_xor(m, 2));
    m = fmaxf(m, __shfl_xor(m, 4));
    float e = expf(li - m);
    float sum = e;
    sum += __shfl_xor(sum, 1);
    sum += __shfl_xor(sum, 2);
    sum += __shfl_xor(sum, 4);
    Wsm[((size_t)s*BSZ + b)*8 + l] = e / sum;
  } else if (l < 40) {
    const int d = l - 8;
    float acc = Sgb[s*32 + d];
    #pragma unroll 4
    for (int q = 0; q < 128; ++q) acc += c[q] * SgW[(size_t)(s*128 + q)*32 + d];
    float sp = fmaxf(acc, 0.f) + log1pf(expf(-fabsf(acc)));  // stable softplus
    float dg = fminf(sp, 1.0f);
    Q2[((size_t)s*BSZ + b)*32 + d] = dg * dg;
  }
}

// ---------------- kA2: ctxT[c][b] = ctx[b][c] ----------------
__global__ __launch_bounds__(256) void kA2(const float* __restrict__ ctx,
                                           float* __restrict__ ctxT) {
  __shared__ float tile[32][33];
  const int bb = blockIdx.x * 32, cc = blockIdx.y * 32;
  const int tx = threadIdx.x & 31, ty = threadIdx.x >> 5;
  for (int r = ty; r < 32; r += 8) tile[r][tx] = ctx[(size_t)(bb + r)*128 + cc + tx];
  __syncthreads();
  for (int r = ty; r < 32; r += 8) ctxT[(size_t)(cc + r)*BSZ + bb + tx] = tile[tx][r];
}

// ---------------- kB0: V2[s][(k,c)][n] = S_W[c][k,n] - S_W[c][k,nT] ----------------
__global__ __launch_bounds__(256) void kB0(const float* __restrict__ SW,
                                           float* __restrict__ V2) {
  const int kc = blockIdx.x, s = blockIdx.y;
  const int k = kc >> 7, c = kc & 127;
  const float* src = SW + ((size_t)(s*128 + c))*8192 + (size_t)k*1024;
  float* dst = V2 + (size_t)s*1048576 + (size_t)kc*1024;
  for (int n = threadIdx.x; n < 1024; n += 256) {
    const int i = n >> 5, j = n & 31;
    dst[n] = src[n] - src[j*32 + i];
  }
}

// ---------------- kB0b: skewed S_b ----------------
__global__ __launch_bounds__(256) void kB0b(const float* __restrict__ Sb,
                                            float* __restrict__ SBsk) {
  const int k = blockIdx.x, s = blockIdx.y;
  const float* src = Sb + (size_t)s*8192 + (size_t)k*1024;
  for (int n = threadIdx.x; n < 1024; n += 256)
    SBsk[(size_t)(s*8 + k)*1024 + n] = src[n] - src[(n & 31)*32 + (n >> 5)];
}

// ---------------- kB2: AS = (w (x) ctx) @ V2 + bias ----------------
__global__ __launch_bounds__(256) void kB2(const float* __restrict__ ctxT,
    const float* __restrict__ Wsm, const float* __restrict__ V2,
    const float* __restrict__ SB, float* __restrict__ AS) {
  __shared__ float At[32][128];
  __shared__ float Bt[32][128];
  __shared__ float wS[8][128];
  __shared__ float sbS[8][128];
  const int t = threadIdx.x;
  const int nb = blockIdx.x * 128, bb = blockIdx.y * 128, s = blockIdx.z;
  for (int i = t; i < 1024; i += 256) {
    const int k = i >> 7, x = i & 127;
    wS[k][x]  = Wsm[((size_t)s*BSZ + bb + x)*8 + k];
    sbS[k][x] = SB[(size_t)(s*8 + k)*1024 + nb + x];
  }
  float acc[8][8] = {};
  const int b0 = (t >> 4) * 8, n0 = (t & 15) * 8;
  const int qrow = t >> 3, x0 = (t & 7) * 16;
  for (int kc0 = 0; kc0 < 1024; kc0 += 32) {
    const int kseg = kc0 >> 7, cbase = kc0 & 127;
    __syncthreads();
    #pragma unroll
    for (int rep = 0; rep < 4; ++rep) {
      const int x = x0 + rep*4;
      const float4 cv = *(const float4*)&ctxT[(size_t)(cbase + qrow)*BSZ + bb + x];
      const float4 wv = *(const float4*)&wS[kseg][x];
      *(float4*)&At[qrow][x] = make_float4(cv.x*wv.x, cv.y*wv.y, cv.z*wv.z, cv.w*wv.w);
      *(float4*)&Bt[qrow][x] =
        *(const float4*)&V2[(size_t)s*1048576 + (size_t)(kc0 + qrow)*1024 + nb + x];
    }
    __syncthreads();
    #pragma unroll 8
    for (int q = 0; q < 32; ++q) {
      float av[8], bv[8];
      ld4(av, &At[q][b0]); ld4(av + 4, &At[q][b0 + 4]);
      ld4(bv, &Bt[q][n0]); ld4(bv + 4, &Bt[q][n0 + 4]);
      #pragma unroll
      for (int i = 0; i < 8; ++i)
        #pragma unroll
        for (int j = 0; j < 8; ++j) acc[i][j] += av[i] * bv[j];
    }
  }
  #pragma unroll
  for (int k = 0; k < 8; ++k) {
    float wv[8], sv[8];
    ld4(wv, &wS[k][b0]); ld4(wv + 4, &wS[k][b0 + 4]);
    ld4(sv, &sbS[k][n0]); ld4(sv + 4, &sbS[k][n0 + 4]);
    #pragma unroll
    for (int i = 0; i < 8; ++i)
      #pragma unroll
      for (int j = 0; j < 8; ++j) acc[i][j] += wv[i] * sv[j];
  }
  for (int i = 0; i < 8; ++i) {
    float* dst = AS + ((size_t)s*BSZ + bb + b0 + i)*1024 + nb + n0;
    st4(dst, acc[i]); st4(dst + 4, &acc[i][4]);
  }
}

// ---------------- kL: Ltil = (ctx@L_W + L_b)*sqrt(w) ----------------
__global__ __launch_bounds__(256) void kL(const float* __restrict__ ctxT,
    const float* __restrict__ LW, const float* __restrict__ Lb,
    const float* __restrict__ Wsm, float* __restrict__ LT, int s) {
  __shared__ float At[32][128];
  __shared__ float Bt[32][128];
  __shared__ float wsq[8][128];
  const int t = threadIdx.x;
  const int nb = blockIdx.x * 128, bb = blockIdx.y * 128;
  for (int i = t; i < 1024; i += 256) {
    const int k = i >> 7, x = i & 127;
    wsq[k][x] = sqrtf(Wsm[((size_t)s*BSZ + bb + x)*8 + k]);
  }
  float acc[8][8] = {};
  const int b0 = (t >> 4) * 8, n0 = (t & 15) * 8;
  const int qrow = t >> 3, x0 = (t & 7) * 16;
  for (int c0 = 0; c0 < 128; c0 += 32) {
    __syncthreads();
    #pragma unroll
    for (int rep = 0; rep < 4; ++rep) {
      const int x = x0 + rep*4;
      *(float4*)&At[qrow][x] = *(const float4*)&ctxT[(size_t)(c0 + qrow)*BSZ + bb + x];
      *(float4*)&Bt[qrow][x] =
        *(const float4*)&LW[((size_t)(s*128 + c0 + qrow))*2048 + nb + x];
    }
    __syncthreads();
    #pragma unroll 8
    for (int q = 0; q < 32; ++q) {
      float av[8], bv[8];
      ld4(av, &At[q][b0]); ld4(av + 4, &At[q][b0 + 4]);
      ld4(bv, &Bt[q][n0]); ld4(bv + 4, &Bt[q][n0 + 4]);
      #pragma unroll
      for (int i = 0; i < 8; ++i)
        #pragma unroll
        for (int j = 0; j < 8; ++j) acc[i][j] += av[i] * bv[j];
    }
  }
  const int kidx = (nb + n0) >> 8;
  const int dcol = ((nb + n0) >> 3) & 31;
  float lbv[8];
  #pragma unroll
  for (int j = 0; j < 8; ++j) lbv[j] = Lb[(size_t)s*2048 + nb + n0 + j];
  for (int i = 0; i < 8; ++i) {
    const float wv = wsq[kidx][b0 + i];
    float* dst = LT + (size_t)(bb + b0 + i)*2048 + kidx*256 + dcol;
    #pragma unroll
    for (int j = 0; j < 8; ++j) dst[j*32] = (acc[i][j] + lbv[j]) * wv;
  }
}

// ---------------- kLLT: AS -= Ltil Ltil^T  (4 b per block) ----------------
__global__ __launch_bounds__(128) void kLLT(const float* __restrict__ LT,
                                            float* __restrict__ AS, int s) {
  __shared__ float L4[4][64][32];
  const int t = threadIdx.x;
  const int bbase = blockIdx.x * 4;
  {
    float* l4f = &L4[0][0][0];
    const float* src = LT + (size_t)bbase * 2048;
    for (int i = t*4; i < 8192; i += 512)
      *(float4*)&l4f[i] = *(const float4*)&src[i];
  }
  __syncthreads();
  const int b = t >> 5, u = t & 31;
  const int i0 = (u >> 2) * 4, j0 = (u & 3) * 8;
  float acc[4][8] = {};
  #pragma unroll 8
  for (int kr = 0; kr < 64; ++kr) {
    float pa[4], pb[8];
    ld4(pa, &L4[b][kr][i0]);
    ld4(pb, &L4[b][kr][j0]); ld4(pb + 4, &L4[b][kr][j0 + 4]);
    #pragma unroll
    for (int ii = 0; ii < 4; ++ii)
      #pragma unroll
      for (int jj = 0; jj < 8; ++jj) acc[ii][jj] += pa[ii] * pb[jj];
  }
  float* dst = AS + ((size_t)s*BSZ + bbase + b)*1024;
  for (int ii = 0; ii < 4; ++ii) {
    float x[8];
    ld4(x, &dst[(i0+ii)*32 + j0]); ld4(x + 4, &dst[(i0+ii)*32 + j0 + 4]);
    #pragma unroll
    for (int jj = 0; jj < 8; ++jj) x[jj] -= acc[ii][jj];
    st4(&dst[(i0+ii)*32 + j0], x); st4(&dst[(i0+ii)*32 + j0 + 4], &x[4]);
  }
}

// ================= kC2: one wave per b =================
// Matmul helpers: C_tile[i][c] += sum_k L[r4+i][k]*R[k][c4+c], reading the
// LEFT operand from its transposed copy LT (row-major b128 reads only).
__device__ __forceinline__ void mm1(const float (*LT)[PAD], const float (*R)[PAD],
                                    float acc[4][4], int r4, int c4) {
  #pragma unroll 2
  for (int k0 = 0; k0 < 32; k0 += 4) {
    float af[4][4], bf[4][4];
    #pragma unroll
    for (int j = 0; j < 4; ++j) {
      ld4(af[j], &LT[k0 + j][r4]);
      ld4(bf[j], &R[k0 + j][c4]);
    }
    #pragma unroll
    for (int j = 0; j < 4; ++j)
      #pragma unroll
      for (int i = 0; i < 4; ++i)
        #pragma unroll
        for (int c = 0; c < 4; ++c) acc[i][c] += af[j][i] * bf[j][c];
  }
}
// shared LEFT, two rights
__device__ __forceinline__ void mm2(const float (*LT)[PAD], const float (*R1)[PAD],
                                    const float (*R2)[PAD],
                                    float a1[4][4], float a2[4][4], int r4, int c4) {
  #pragma unroll 2
  for (int k0 = 0; k0 < 32; k0 += 4) {
    float af[4][4], b1[4][4], b2[4][4];
    #pragma unroll
    for (int j = 0; j < 4; ++j) {
      ld4(af[j], &LT[k0 + j][r4]);
      ld4(b1[j], &R1[k0 + j][c4]);
      ld4(b2[j], &R2[k0 + j][c4]);
    }
    #pragma unroll
    for (int j = 0; j < 4; ++j)
      #pragma unroll
      for (int i = 0; i < 4; ++i)
        #pragma unroll
        for (int c = 0; c < 4; ++c) {
          a1[i][c] += af[j][i] * b1[j][c];
          a2[i][c] += af[j][i] * b2[j][c];
        }
  }
}
// two lefts, shared RIGHT
__device__ __forceinline__ void mm2r(const float (*L1T)[PAD], const float (*L2T)[PAD],
                                     const float (*R)[PAD],
                                     float a1[4][4], float a2[4][4], int r4, int c4) {
  #pragma unroll 2
  for (int k0 = 0; k0 < 32; k0 += 4) {
    float a1f[4][4], a2f[4][4], bf[4][4];
    #pragma unroll
    for (int j = 0; j < 4; ++j) {
      ld4(a1f[j], &L1T[k0 + j][r4]);
      ld4(a2f[j], &L2T[k0 + j][r4]);
      ld4(bf[j], &R[k0 + j][c4]);
    }
    #pragma unroll
    for (int j = 0; j < 4; ++j)
      #pragma unroll
      for (int i = 0; i < 4; ++i)
        #pragma unroll
        for (int c = 0; c < 4; ++c) {
          a1[i][c] += a1f[j][i] * bf[j][c];
          a2[i][c] += a2f[j][i] * bf[j][c];
        }
  }
}
__device__ __forceinline__ void stR(float (*M)[PAD], const float T[4][4], int r4, int c4) {
  #pragma unroll
  for (int i = 0; i < 4; ++i) st4(&M[r4 + i][c4], T[i]);
}
__device__ __forceinline__ void stT(float (*M)[PAD], const float T[4][4], int r4, int c4) {
  #pragma unroll
  for (int j = 0; j < 4; ++j) {
    float col[4] = {T[0][j], T[1][j], T[2][j], T[3][j]};
    st4(&M[c4 + j][r4], col);
  }
}

__global__ __launch_bounds__(64) void kC2(const float* __restrict__ AS,
    const float* __restrict__ Q2, const float* __restrict__ z0,
    float* __restrict__ out) {
  // 7 matrix buffers, pad 36 (rows 144B, 16B-aligned, conflict-free b128 rows)
  __shared__ float b_a[32][PAD], b_at[32][PAD];   // a,aT; later R11T,R12T
  __shared__ float b_r11[32][PAD], b_r12[32][PAD], b_r22[32][PAD];
  __shared__ float b_x[32][PAD];                  // R22T; later transpose scratch
  __shared__ float b_cov[32][PAD];
  __shared__ float zarr[32], qds[32];
  const int b = blockIdx.x, t = threadIdx.x;
  const int r4 = (t >> 3) * 4, c4 = (t & 7) * 4;

  if (t < 32) zarr[t] = z0[(size_t)b*32 + t];
  {
    const float zz[4] = {0.f, 0.f, 0.f, 0.f};
    #pragma unroll
    for (int i = 0; i < 4; ++i) st4(&b_cov[r4 + i][c4], zz);
  }
  __syncthreads();

  float* covout = out + 3145728 + (size_t)b*24576;
  float* stout  = out + (size_t)b*768;

  for (int s = 0; s < NSEGC; ++s) {
    // ---- load A tile, frob clamp, scale, write a/aT, init R ----
    if (t < 32) qds[t] = Q2[((size_t)s*BSZ + b)*32 + t] * XSC;
    const float* asb = AS + ((size_t)s*BSZ + b)*1024;
    float Atile[4][4];
    #pragma unroll
    for (int i = 0; i < 4; ++i) ld4(Atile[i], &asb[(r4 + i)*32 + c4]);
    #pragma unroll
    for (int i = 0; i < 4; ++i)
      #pragma unroll
      for (int j = 0; j < 4; ++j) if (r4 + i == c4 + j) Atile[i][j] -= MUC;
    float ssq = 0.f;
    #pragma unroll
    for (int i = 0; i < 4; ++i)
      #pragma unroll
      for (int j = 0; j < 4; ++j) ssq += Atile[i][j]*Atile[i][j];
    #pragma unroll
    for (int off = 1; off < 64; off <<= 1) ssq += __shfl_xor(ssq, off);
    const float frob = sqrtf(ssq);
    const float sc = (frob > 3.0f ? 3.0f / (frob + 1e-6f) : 1.0f) * XSC;
    float av[4][4], id[4][4], zo[4][4];
    #pragma unroll
    for (int i = 0; i < 4; ++i)
      #pragma unroll
      for (int j = 0; j < 4; ++j) {
        av[i][j] = Atile[i][j] * sc;
        id[i][j] = (r4 + i == c4 + j) ? 1.f : 0.f;
        zo[i][j] = 0.f;
      }
    stR(b_a, av, r4, c4);  stT(b_at, av, r4, c4);
    stR(b_r11, id, r4, c4); stR(b_r22, id, r4, c4); stR(b_r12, zo, r4, c4);
    __syncthreads();

    // ---- Taylor Horner ORDER=6: R = I + X@R/k ----
    #pragma unroll
    for (int k = 6; k >= 1; --k) {
      float A11[4][4] = {}, A12[4][4] = {}, A22[4][4] = {};
      mm2(b_at, b_r11, b_r12, A11, A12, r4, c4);   // a@R11, a@R12
      mm1(b_a, b_r22, A22, r4, c4);                 // a^T@R22
      #pragma unroll
      for (int i = 0; i < 4; ++i) {                 // + q@R22 (diag row-scale)
        float rv[4]; ld4(rv, &b_r22[r4 + i][c4]);
        const float qv = qds[r4 + i];
        #pragma unroll
        for (int c = 0; c < 4; ++c) A12[i][c] += qv * rv[c];
      }
      const float rk = 1.0f / (float)k;
      #pragma unroll
      for (int i = 0; i < 4; ++i)
        #pragma unroll
        for (int c = 0; c < 4; ++c) {
          const float e = (r4 + i == c4 + c) ? 1.f : 0.f;
          A11[i][c] = A11[i][c]*rk + e;
          A12[i][c] = A12[i][c]*rk;
          A22[i][c] = e - A22[i][c]*rk;             // I + (-a^T@R22)/k
        }
      __syncthreads();
      stR(b_r11, A11, r4, c4); stR(b_r12, A12, r4, c4); stR(b_r22, A22, r4, c4);
      if (k == 1) {  // build T-copies for squaring: R11T->b_a, R12T->b_at, R22T->b_x
        stT(b_a, A11, r4, c4); stT(b_at, A12, r4, c4); stT(b_x, A22, r4, c4);
      }
      __syncthreads();
    }

    // ---- 2 squarings (block upper-triangular) ----
    #pragma unroll
    for (int sq = 0; sq < 2; ++sq) {
      float A11[4][4] = {}, A12[4][4] = {}, A22[4][4] = {};
      mm2(b_a, b_r11, b_r12, A11, A12, r4, c4);    // R11@R11, R11@R12
      mm2r(b_at, b_x, b_r22, A12, A22, r4, c4);    // R12@R22, R22@R22
      __syncthreads();
      stR(b_r11, A11, r4, c4); stT(b_a, A11, r4, c4);
      stR(b_r12, A12, r4, c4); stT(b_at, A12, r4, c4);
      stR(b_r22, A22, r4, c4); stT(b_x, A22, r4, c4);
      __syncthreads();
    }

    // ---- Qd = 0.5*(Phi@E12 + (Phi@E12)^T) -> b_r22 ----
    {
      float QA[4][4] = {};
      mm1(b_a, b_r12, QA, r4, c4);                  // Phi@E12 (left PhiT=b_a)
      stT(b_x, QA, r4, c4);
      __syncthreads();
      float ct[4], qd_[4][4];
      #pragma unroll
      for (int i = 0; i < 4; ++i) {
        ld4(ct, &b_x[r4 + i][c4]);
        #pragma unroll
        for (int c = 0; c < 4; ++c) qd_[i][c] = 0.5f * (QA[i][c] + ct[c]);
      }
      stR(b_r22, qd_, r4, c4);
      __syncthreads();
    }

    // ---- 8 propagation steps ----
    for (int tt = 0; tt < 8; ++tt) {
      float T1[4][4] = {};
      mm1(b_a, b_cov, T1, r4, c4);                  // T1 = Phi@cov
      __syncthreads();
      stT(b_at, T1, r4, c4);                        // only T1T needed
      __syncthreads();
      float Cc[4][4] = {};
      mm1(b_at, b_a, Cc, r4, c4);                   // C = T1@Phi^T (B rows = b_a)
      // z' = Phi@z (rows from b_r11, half-split across lane halves)
      const int zr = t & 31, zh = (t >> 5) * 16;
      float zp = 0.f;
      #pragma unroll
      for (int q4 = 0; q4 < 4; ++q4) {
        float pv[4], zz[4];
        ld4(pv, &b_r11[zr][zh + q4*4]);
        ld4(zz, &zarr[zh + q4*4]);
        #pragma unroll
        for (int e = 0; e < 4; ++e) zp += pv[e] * zz[e];
      }
      zp += __shfl_xor(zp, 32);
      stT(b_x, Cc, r4, c4);
      __syncthreads();
      float cv[4][4];
      #pragma unroll
      for (int i = 0; i < 4; ++i) {
        float ct[4], qv[4];
        ld4(ct, &b_x[r4 + i][c4]);
        ld4(qv, &b_r22[r4 + i][c4]);
        #pragma unroll
        for (int c = 0; c < 4; ++c) cv[i][c] = 0.5f * (Cc[i][c] + ct[c]) + qv[c];
      }
      stR(b_cov, cv, r4, c4);
      float* cb = covout + (size_t)(s*8 + tt)*1024;
      #pragma unroll
      for (int i = 0; i < 4; ++i) st4(&cb[(r4 + i)*32 + c4], cv[i]);
      if (t < 32) {
        zarr[t] = zp;
        stout[(s*8 + tt)*32 + t] = zp;
      }
      __syncthreads();
    }
  }
}

// ---------------- launch ----------------
extern "C" void kernel_launch(void* const* d_in, const int* in_sizes, int n_in,
                              void* d_out, int out_size, void* d_ws, size_t ws_size,
                              hipStream_t stream) {
  const float* ctx  = (const float*)d_in[0];
  const float* z0   = (const float*)d_in[1];
  const float* S_W  = (const float*)d_in[2];
  const float* S_b  = (const float*)d_in[3];
  const float* L_W  = (const float*)d_in[4];
  const float* L_b  = (const float*)d_in[5];
  const float* G_W  = (const float*)d_in[6];
  const float* G_b  = (const float*)d_in[7];
  const float* Sg_W = (const float*)d_in[8];
  const float* Sg_b = (const float*)d_in[9];
  float* out = (float*)d_out;
  float* ws  = (float*)d_ws;

  float* w_   = ws;                 // [3][4096][8]
  float* q2   = ws + 98304;         // [3][4096][32]
  float* ctxT = ws + 491520;        // [128][4096]
  float* sbsk = ws + 1015808;       // [3][8][1024]
  float* v2   = ws + 1040384;       // [3][1024][1024]
  float* as_  = ws + 4186112;       // [3][4096][1024]
  float* lt   = ws + 16769024;      // [4096][2048] (per-seg reuse)

  kA  <<<dim3(4096, 3), 64,  0, stream>>>(ctx, G_W, G_b, Sg_W, Sg_b, w_, q2);
  kA2 <<<dim3(128, 4),  256, 0, stream>>>(ctx, ctxT);
  kB0 <<<dim3(1024, 3), 256, 0, stream>>>(S_W, v2);
  kB0b<<<dim3(8, 3),    256, 0, stream>>>(S_b, sbsk);
  kB2 <<<dim3(8, 32, 3),256, 0, stream>>>(ctxT, w_, v2, sbsk, as_);
  for (int s = 0; s < 3; ++s) {
    kL  <<<dim3(16, 32), 256, 0, stream>>>(ctxT, L_W, L_b, w_, lt, s);
    kLLT<<<dim3(1024),   128, 0, stream>>>(lt, as_, s);
  }
  kC2 <<<dim3(4096),    64, 0, stream>>>(as_, q2, z0, out);
}